// Round 1
// baseline (390.575 us; speedup 1.0000x reference)
//
#include <hip/hip_runtime.h>
#include <math.h>

typedef __attribute__((ext_vector_type(8))) short bf16x8;
typedef __attribute__((ext_vector_type(4))) float f32x4;

#define DEV __device__ __forceinline__

DEV unsigned short f2b(float f) {
    union { float f; unsigned u; } x;
    x.f = f;
    unsigned r = x.u + 0x7fff + ((x.u >> 16) & 1);  // RNE
    return (unsigned short)(r >> 16);
}
DEV float b2f(unsigned short u) {
    union { unsigned u; float f; } x;
    x.u = ((unsigned)u) << 16;
    return x.f;
}

// async global->LDS, 16B per lane; LDS dest must be wave-uniform base + lane*16
DEV void glds16(const void* g, void* l) {
    __builtin_amdgcn_global_load_lds(
        (const __attribute__((address_space(1))) void*)g,
        (__attribute__((address_space(3))) void*)l, 16, 0, 0);
}

// ---------------------------------------------------------------------------
// P0a: fp32 -> bf16 elementwise (X pre-convert)
// ---------------------------------------------------------------------------
__global__ __launch_bounds__(256) void cvt_bf16(
    const float* __restrict__ in, unsigned short* __restrict__ out)
{
    int i = (blockIdx.x * 256 + threadIdx.x) * 8;
    float4 a = *(const float4*)(in + i);
    float4 b = *(const float4*)(in + i + 4);
    int4 tv;
    short* tp = reinterpret_cast<short*>(&tv);
    tp[0] = (short)f2b(a.x); tp[1] = (short)f2b(a.y);
    tp[2] = (short)f2b(a.z); tp[3] = (short)f2b(a.w);
    tp[4] = (short)f2b(b.x); tp[5] = (short)f2b(b.y);
    tp[6] = (short)f2b(b.z); tp[7] = (short)f2b(b.w);
    *(int4*)(out + i) = tv;
}

// ---------------------------------------------------------------------------
// P0b: W fp32 [1024][N] -> W^T bf16 [N][1024]   (64x64 LDS tiles)
// ---------------------------------------------------------------------------
__global__ __launch_bounds__(256) void transpose_cvt(
    const float* __restrict__ W, unsigned short* __restrict__ Wt, int N)
{
    __shared__ short S[64 * 65];
    const int n0 = blockIdx.x * 64, k0 = blockIdx.y * 64;
    const int tid = threadIdx.x;
#pragma unroll
    for (int p = 0; p < 16; p++) {
        int idx = p * 256 + tid;
        int r = idx >> 6, c = idx & 63;          // r = k, c = n (coalesced read)
        S[c * 65 + r] = (short)f2b(W[(size_t)(k0 + r) * N + n0 + c]);
    }
    __syncthreads();
#pragma unroll
    for (int p = 0; p < 8; p++) {
        int idx = p * 256 + tid;
        int r = idx >> 5, cp = (idx & 31) * 2;   // r = n, cp = k pair
        unsigned lo = (unsigned short)S[r * 65 + cp];
        unsigned hi = (unsigned short)S[r * 65 + cp + 1];
        *(unsigned*)(Wt + (size_t)(n0 + r) * 1024 + k0 + cp) = lo | (hi << 16);
    }
}

// ---------------------------------------------------------------------------
// K1: QKV GEMM (all bf16). C[8192,3072] = Xb @ Wt^T + b
// Q,K scattered to [B,H,S,hd]; V scattered TRANSPOSED to Vt[B,H,hd,S]
// (b64 packed stores) so attn can read V^T fragments directly.
// ---------------------------------------------------------------------------
__global__ __launch_bounds__(256) void qkv_gemm(
    const unsigned short* __restrict__ Xb,   // [8192][1024] bf16
    const unsigned short* __restrict__ Wt,   // [3072][1024] bf16 = W^T
    const float* __restrict__ bq,
    unsigned short* __restrict__ Qb,
    unsigned short* __restrict__ Kb,
    unsigned short* __restrict__ Vt)         // [128][64][1024] bf16
{
    __shared__ __align__(16) short As[128 * 64];
    __shared__ __align__(16) short Bs[128 * 64];

    const int m0 = blockIdx.y * 128, n0 = blockIdx.x * 128;
    const int tid = threadIdx.x;
    const int wave = tid >> 6, lane = tid & 63;
    const int quad = lane >> 4, lcol = lane & 15;
    const int wrow = (wave >> 1) * 64, wcol = (wave & 1) * 64;

    f32x4 acc[4][4];
#pragma unroll
    for (int i = 0; i < 4; i++)
#pragma unroll
        for (int j = 0; j < 4; j++) acc[i][j] = (f32x4){0.f, 0.f, 0.f, 0.f};

    const int sr = tid >> 3;          // 0..31: row within 32-row pass
    const int sc8 = (tid & 7) * 8;    // col (shorts)

    for (int k0 = 0; k0 < 1024; k0 += 64) {
        __syncthreads();
#pragma unroll
        for (int p = 0; p < 4; p++) {
            glds16(Xb + (size_t)(m0 + p * 32 + sr) * 1024 + k0 + sc8,
                   &As[(p * 32 + sr) * 64 + sc8]);
            glds16(Wt + (size_t)(n0 + p * 32 + sr) * 1024 + k0 + sc8,
                   &Bs[(p * 32 + sr) * 64 + sc8]);
        }
        __syncthreads();
#pragma unroll
        for (int kk = 0; kk < 2; kk++) {
            int ko = kk * 32 + quad * 8;
            bf16x8 a[4], b[4];
#pragma unroll
            for (int i = 0; i < 4; i++)
                a[i] = *(const bf16x8*)(&As[(wrow + 16 * i + lcol) * 64 + ko]);
#pragma unroll
            for (int j = 0; j < 4; j++)
                b[j] = *(const bf16x8*)(&Bs[(wcol + 16 * j + lcol) * 64 + ko]);
#pragma unroll
            for (int i = 0; i < 4; i++)
#pragma unroll
                for (int j = 0; j < 4; j++)
                    acc[i][j] = __builtin_amdgcn_mfma_f32_16x16x32_bf16(
                        a[i], b[j], acc[i][j], 0, 0, 0);
        }
    }

    // epilogue: +bias (fp32); Q,K -> [B,H,S,hd]; V -> Vt[B,H,hd,S] (b64)
#pragma unroll
    for (int j = 0; j < 4; j++) {
        int c = n0 + wcol + 16 * j + lcol;      // [0,3072)
        float bias = bq[c];
        int which = c >> 10, d = c & 1023;
        int h = d >> 6, e = d & 63;
        if (which < 2) {
            unsigned short* dst = (which == 0) ? Qb : Kb;
#pragma unroll
            for (int i = 0; i < 4; i++) {
#pragma unroll
                for (int reg = 0; reg < 4; reg++) {
                    int r = m0 + wrow + 16 * i + quad * 4 + reg;   // [0,8192)
                    int b = r >> 10, s = r & 1023;
                    float v = acc[i][j][reg] + bias;
                    dst[(size_t)((b * 16 + h) * 1024 + s) * 64 + e] = f2b(v);
                }
            }
        } else {
#pragma unroll
            for (int i = 0; i < 4; i++) {
                int r0 = m0 + wrow + 16 * i + quad * 4;
                int b = r0 >> 10, s0 = r0 & 1023;
                ushort4 pk;
                pk.x = f2b(acc[i][j][0] + bias);
                pk.y = f2b(acc[i][j][1] + bias);
                pk.z = f2b(acc[i][j][2] + bias);
                pk.w = f2b(acc[i][j][3] + bias);
                *(ushort4*)(Vt + (size_t)((b * 16 + h) * 64 + e) * 1024 + s0) = pk;
            }
        }
    }
}

// ---------------------------------------------------------------------------
// K2: causal flash attention — BARRIER-FREE wave-independent version.
// 128 q-rows/block (32/wave), grid (8 qt heavy-first, 128 bh).
// Per-head K (128 KB) and V^T (128 KB) are L2/L3-resident -> no LDS staging
// for V; each wave reads its K and V^T fragments straight from global.
// Ps is wave-private (wave w touches only rows [32w,32w+32)), so there is
// NO cross-wave LDS dependency and NO __syncthreads in the k-loop: the 4
// waves free-run and mutually hide global-load latency. LDS 34.8 KB ->
// 4 blocks/CU (VGPR-limited), vs 3 before, with zero barrier convoys.
// ---------------------------------------------------------------------------
__global__ __launch_bounds__(256) void attn_kern(
    const unsigned short* __restrict__ Qb,
    const unsigned short* __restrict__ Kb,
    const unsigned short* __restrict__ Vt,
    unsigned short* __restrict__ Ob)
{
    __shared__ __align__(16) short Ps[128 * 136];   // P: [q][key], 34.8 KB

    const int qt = 7 - blockIdx.x;                  // heavy blocks first
    const int bh = blockIdx.y;
    const int q0 = qt * 128;
    const unsigned short* Qp = Qb + (size_t)bh * 65536;
    const unsigned short* Kp = Kb + (size_t)bh * 65536;
    const unsigned short* Vp = Vt + (size_t)bh * 65536;

    const int tid = threadIdx.x;
    const int wave = tid >> 6, lane = tid & 63;
    const int quad = lane >> 4, lcol = lane & 15;

    // Q fragments (A-layout: m=lane&15, k=quad*8+j); wave owns 32 q-rows
    bf16x8 qa[2][2];
#pragma unroll
    for (int i = 0; i < 2; i++)
#pragma unroll
        for (int kk = 0; kk < 2; kk++)
            qa[i][kk] = *(const bf16x8*)(Qp + (size_t)(q0 + wave * 32 + 16 * i + lcol) * 64
                                         + kk * 32 + quad * 8);

    f32x4 o_acc[2][4];
#pragma unroll
    for (int i = 0; i < 2; i++)
#pragma unroll
        for (int jo = 0; jo < 4; jo++) o_acc[i][jo] = (f32x4){0.f, 0.f, 0.f, 0.f};
    float l_loc[2][4];
#pragma unroll
    for (int i = 0; i < 2; i++)
#pragma unroll
        for (int r = 0; r < 4; r++) l_loc[i][r] = 0.f;

    const float sc2 = 0.0450711882f;  // log2(e)/32  (scale folded into exp2)

    for (int kt = 0; kt <= qt; kt++) {
        const bool diag = (kt == qt);
        const int jstore = diag ? (2 * wave + 1) : 7;   // max live j-tile

        // S = Q K^T  (K natural layout == B^T operand, streamed from global)
        f32x4 sc[2][8];
#pragma unroll
        for (int i = 0; i < 2; i++)
#pragma unroll
            for (int j = 0; j < 8; j++) sc[i][j] = (f32x4){0.f, 0.f, 0.f, 0.f};
#pragma unroll
        for (int kk = 0; kk < 2; kk++) {
            bf16x8 kb[8];
#pragma unroll
            for (int j = 0; j < 8; j++)
                if (j <= jstore)
                    kb[j] = *(const bf16x8*)(Kp + (size_t)(kt * 128 + 16 * j + lcol) * 64
                                             + kk * 32 + quad * 8);
#pragma unroll
            for (int i = 0; i < 2; i++)
#pragma unroll
                for (int j = 0; j < 8; j++)
                    if (j <= (diag ? (2 * wave + i) : 7))
                        sc[i][j] = __builtin_amdgcn_mfma_f32_16x16x32_bf16(
                            qa[i][kk], kb[j], sc[i][j], 0, 0, 0);
        }

        // max-free softmax: p = exp2(s*log2e/32), l accumulates lane-locally.
        // Ps rows written here belong to THIS wave only; the compiler's
        // may-alias lgkmcnt waits order the write->read (in-order DS pipe,
        // wave-lockstep) -- no barrier needed.
#pragma unroll
        for (int i = 0; i < 2; i++) {
#pragma unroll
            for (int reg = 0; reg < 4; reg++) {
                int prow = wave * 32 + 16 * i + quad * 4 + reg;  // local q row
                float rsum = 0.f;
#pragma unroll
                for (int j = 0; j < 8; j++) {
                    if (j <= jstore) {
                        float p = exp2f(sc[i][j][reg] * sc2);
                        if (diag && (16 * j + lcol) > prow) p = 0.f;
                        rsum += p;
                        Ps[prow * 136 + 16 * j + lcol] = (short)f2b(p);
                    }
                }
                l_loc[i][reg] += rsum;
            }
        }

        // O += P @ V   (P A-layout from wave-private Ps rows; V^T fragments
        // direct from global: per quad a 64B-contiguous segment, L1/L2-hot)
#pragma unroll
        for (int kk2 = 0; kk2 < 4; kk2++) {
            if (!diag || kk2 <= wave) {
                bf16x8 pa[2], vb[4];
#pragma unroll
                for (int i = 0; i < 2; i++)
                    pa[i] = *(const bf16x8*)(&Ps[(wave * 32 + 16 * i + lcol) * 136
                                                 + kk2 * 32 + quad * 8]);
#pragma unroll
                for (int jo = 0; jo < 4; jo++)
                    vb[jo] = *(const bf16x8*)(Vp + (size_t)(16 * jo + lcol) * 1024
                                              + kt * 128 + kk2 * 32 + quad * 8);
#pragma unroll
                for (int i = 0; i < 2; i++)
#pragma unroll
                    for (int jo = 0; jo < 4; jo++)
                        o_acc[i][jo] = __builtin_amdgcn_mfma_f32_16x16x32_bf16(
                            pa[i], vb[jo], o_acc[i][jo], 0, 0, 0);
            }
        }
    }

    // single final l reduction (16 lanes of a quad share a row)
#pragma unroll
    for (int i = 0; i < 2; i++)
#pragma unroll
        for (int reg = 0; reg < 4; reg++) {
            float l = l_loc[i][reg];
            l += __shfl_xor(l, 1);
            l += __shfl_xor(l, 2);
            l += __shfl_xor(l, 4);
            l += __shfl_xor(l, 8);
            l_loc[i][reg] = l;
        }

    // write O -> [B, S, H*hd] bf16
    const int b = bh >> 4, h = bh & 15;
#pragma unroll
    for (int i = 0; i < 2; i++) {
#pragma unroll
        for (int reg = 0; reg < 4; reg++) {
            int q = q0 + wave * 32 + 16 * i + quad * 4 + reg;
            float inv = 1.0f / l_loc[i][reg];
#pragma unroll
            for (int jo = 0; jo < 4; jo++) {
                int e = 16 * jo + lcol;
                Ob[(size_t)(b * 1024 + q) * 1024 + h * 64 + e] =
                    f2b(o_acc[i][jo][reg] * inv);
            }
        }
    }
}

// ---------------------------------------------------------------------------
// K3: out proj. P2[8192,1024](bf16) = O @ Wout + bout + X(fp32 residual)
// ---------------------------------------------------------------------------
__global__ __launch_bounds__(256) void out_gemm(
    const unsigned short* __restrict__ O,
    const unsigned short* __restrict__ Wt2,  // [1024][1024] bf16 = Wout^T
    const float* __restrict__ bo,
    const float* __restrict__ X,
    unsigned short* __restrict__ P2)
{
    __shared__ __align__(16) short As[128 * 64];
    __shared__ __align__(16) short Bs[128 * 64];

    const int m0 = blockIdx.y * 128, n0 = blockIdx.x * 128;
    const int tid = threadIdx.x;
    const int wave = tid >> 6, lane = tid & 63;
    const int quad = lane >> 4, lcol = lane & 15;
    const int wrow = (wave >> 1) * 64, wcol = (wave & 1) * 64;

    f32x4 acc[4][4];
#pragma unroll
    for (int i = 0; i < 4; i++)
#pragma unroll
        for (int j = 0; j < 4; j++) acc[i][j] = (f32x4){0.f, 0.f, 0.f, 0.f};

    const int sr = tid >> 3;
    const int sc8 = (tid & 7) * 8;

    for (int k0 = 0; k0 < 1024; k0 += 64) {
        __syncthreads();
#pragma unroll
        for (int p = 0; p < 4; p++) {
            glds16(O + (size_t)(m0 + p * 32 + sr) * 1024 + k0 + sc8,
                   &As[(p * 32 + sr) * 64 + sc8]);
            glds16(Wt2 + (size_t)(n0 + p * 32 + sr) * 1024 + k0 + sc8,
                   &Bs[(p * 32 + sr) * 64 + sc8]);
        }
        __syncthreads();
#pragma unroll
        for (int kk = 0; kk < 2; kk++) {
            int ko = kk * 32 + quad * 8;
            bf16x8 a[4], b[4];
#pragma unroll
            for (int i = 0; i < 4; i++)
                a[i] = *(const bf16x8*)(&As[(wrow + 16 * i + lcol) * 64 + ko]);
#pragma unroll
            for (int j = 0; j < 4; j++)
                b[j] = *(const bf16x8*)(&Bs[(wcol + 16 * j + lcol) * 64 + ko]);
#pragma unroll
            for (int i = 0; i < 4; i++)
#pragma unroll
                for (int j = 0; j < 4; j++)
                    acc[i][j] = __builtin_amdgcn_mfma_f32_16x16x32_bf16(
                        a[i], b[j], acc[i][j], 0, 0, 0);
        }
    }

#pragma unroll
    for (int j = 0; j < 4; j++) {
        int c = n0 + wcol + 16 * j + lcol;
        float bias = bo[c];
#pragma unroll
        for (int i = 0; i < 4; i++) {
#pragma unroll
            for (int reg = 0; reg < 4; reg++) {
                int r = m0 + wrow + 16 * i + quad * 4 + reg;
                float v = acc[i][j][reg] + bias + X[(size_t)r * 1024 + c];
                P2[(size_t)r * 1024 + c] = f2b(v);
            }
        }
    }
}

// ---------------------------------------------------------------------------
// K4: LayerNorm over last dim (1024), bf16 in / fp32 out, one block per row
// ---------------------------------------------------------------------------
__global__ __launch_bounds__(256) void ln_kern(
    const unsigned short* __restrict__ P2,
    const float* __restrict__ G,
    const float* __restrict__ Bt,
    float* __restrict__ out)
{
    const int row = blockIdx.x, tid = threadIdx.x;
    const size_t base = (size_t)row * 1024 + tid * 4;

    int2 raw = *(const int2*)(P2 + base);
    float v[4];
    v[0] = b2f((unsigned short)(raw.x & 0xffff));
    v[1] = b2f((unsigned short)((unsigned)raw.x >> 16));
    v[2] = b2f((unsigned short)(raw.y & 0xffff));
    v[3] = b2f((unsigned short)((unsigned)raw.y >> 16));

    float sum = v[0] + v[1] + v[2] + v[3];
    float sq = v[0] * v[0] + v[1] * v[1] + v[2] * v[2] + v[3] * v[3];
#pragma unroll
    for (int m = 1; m < 64; m <<= 1) {
        sum += __shfl_xor(sum, m);
        sq += __shfl_xor(sq, m);
    }
    __shared__ float rs[4], rq[4];
    const int wave = tid >> 6, lane = tid & 63;
    if (lane == 0) { rs[wave] = sum; rq[wave] = sq; }
    __syncthreads();
    sum = rs[0] + rs[1] + rs[2] + rs[3];
    sq = rq[0] + rq[1] + rq[2] + rq[3];

    float mean = sum * (1.0f / 1024.0f);
    float var = fmaxf(sq * (1.0f / 1024.0f) - mean * mean, 0.0f);
    float rstd = rsqrtf(var + 1e-5f);

    float4 g = *(const float4*)(G + tid * 4);
    float4 be = *(const float4*)(Bt + tid * 4);

    float4 o;
    o.x = (v[0] - mean) * rstd * g.x + be.x;
    o.y = (v[1] - mean) * rstd * g.y + be.y;
    o.z = (v[2] - mean) * rstd * g.z + be.z;
    o.w = (v[3] - mean) * rstd * g.w + be.w;
    *(float4*)(out + base) = o;
}

// ---------------------------------------------------------------------------
// Buffer plan:
//   d_out (32 MB): Qb bf16 @0, Ob bf16 @16M; final fp32 result overwrites.
//   d_ws  (56 MB): Kb @0, Vt @16M, Wt2 @32M (2M), Xb @34M (16M), Wt @50M (6M)
//   P2 bf16 @34M aliases Xb (dead after qkv_gemm).
// ---------------------------------------------------------------------------
extern "C" void kernel_launch(void* const* d_in, const int* in_sizes, int n_in,
                              void* d_out, int out_size, void* d_ws, size_t ws_size,
                              hipStream_t stream) {
    const float* x    = (const float*)d_in[0];
    const float* Wqkv = (const float*)d_in[1];
    const float* bqkv = (const float*)d_in[2];
    const float* Wout = (const float*)d_in[3];
    const float* bout = (const float*)d_in[4];
    const float* gam  = (const float*)d_in[5];
    const float* bet  = (const float*)d_in[6];
    float* out = (float*)d_out;

    char* ws = (char*)d_ws;
    const size_t MB = (size_t)1024 * 1024;

    unsigned short* Qb  = (unsigned short*)d_out;
    unsigned short* Ob  = (unsigned short*)d_out + 8388608;
    unsigned short* Kb  = (unsigned short*)(ws);
    unsigned short* Vt  = (unsigned short*)(ws + 16 * MB);
    unsigned short* Wt2 = (unsigned short*)(ws + 32 * MB);
    unsigned short* Xb  = (unsigned short*)(ws + 34 * MB);
    unsigned short* Wt  = (unsigned short*)(ws + 50 * MB);
    unsigned short* P2  = (unsigned short*)(ws + 34 * MB);   // alias Xb

    cvt_bf16<<<4096, 256, 0, stream>>>(x, Xb);
    transpose_cvt<<<dim3(48, 16), 256, 0, stream>>>(Wqkv, Wt, 3072);
    transpose_cvt<<<dim3(16, 16), 256, 0, stream>>>(Wout, Wt2, 1024);
    qkv_gemm<<<dim3(24, 64), 256, 0, stream>>>(Xb, Wt, bqkv, Qb, Kb, Vt);
    attn_kern<<<dim3(8, 128), 256, 0, stream>>>(Qb, Kb, Vt, Ob);
    out_gemm<<<dim3(8, 64), 256, 0, stream>>>(Ob, Wt2, bout, x, P2);
    ln_kern<<<8192, 256, 0, stream>>>(P2, gam, bet, out);
}

// Round 2
// 322.236 us; speedup vs baseline: 1.2121x; 1.2121x over previous
//
#include <hip/hip_runtime.h>
#include <math.h>

typedef __attribute__((ext_vector_type(8))) short bf16x8;
typedef __attribute__((ext_vector_type(4))) float f32x4;

#define DEV __device__ __forceinline__

DEV unsigned short f2b(float f) {
    union { float f; unsigned u; } x;
    x.f = f;
    unsigned r = x.u + 0x7fff + ((x.u >> 16) & 1);  // RNE
    return (unsigned short)(r >> 16);
}
DEV float b2f(unsigned short u) {
    union { unsigned u; float f; } x;
    x.u = ((unsigned)u) << 16;
    return x.f;
}

// async global->LDS, 16B per lane; LDS dest must be wave-uniform base + lane*16
DEV void glds16(const void* g, void* l) {
    __builtin_amdgcn_global_load_lds(
        (const __attribute__((address_space(1))) void*)g,
        (__attribute__((address_space(3))) void*)l, 16, 0, 0);
}

// ---------------------------------------------------------------------------
// P0a: fp32 -> bf16 elementwise (X pre-convert)
// ---------------------------------------------------------------------------
__global__ __launch_bounds__(256) void cvt_bf16(
    const float* __restrict__ in, unsigned short* __restrict__ out)
{
    int i = (blockIdx.x * 256 + threadIdx.x) * 8;
    float4 a = *(const float4*)(in + i);
    float4 b = *(const float4*)(in + i + 4);
    int4 tv;
    short* tp = reinterpret_cast<short*>(&tv);
    tp[0] = (short)f2b(a.x); tp[1] = (short)f2b(a.y);
    tp[2] = (short)f2b(a.z); tp[3] = (short)f2b(a.w);
    tp[4] = (short)f2b(b.x); tp[5] = (short)f2b(b.y);
    tp[6] = (short)f2b(b.z); tp[7] = (short)f2b(b.w);
    *(int4*)(out + i) = tv;
}

// ---------------------------------------------------------------------------
// P0b: W fp32 [1024][N] -> W^T bf16 [N][1024]   (64x64 LDS tiles)
// ---------------------------------------------------------------------------
__global__ __launch_bounds__(256) void transpose_cvt(
    const float* __restrict__ W, unsigned short* __restrict__ Wt, int N)
{
    __shared__ short S[64 * 65];
    const int n0 = blockIdx.x * 64, k0 = blockIdx.y * 64;
    const int tid = threadIdx.x;
#pragma unroll
    for (int p = 0; p < 16; p++) {
        int idx = p * 256 + tid;
        int r = idx >> 6, c = idx & 63;          // r = k, c = n (coalesced read)
        S[c * 65 + r] = (short)f2b(W[(size_t)(k0 + r) * N + n0 + c]);
    }
    __syncthreads();
#pragma unroll
    for (int p = 0; p < 8; p++) {
        int idx = p * 256 + tid;
        int r = idx >> 5, cp = (idx & 31) * 2;   // r = n, cp = k pair
        unsigned lo = (unsigned short)S[r * 65 + cp];
        unsigned hi = (unsigned short)S[r * 65 + cp + 1];
        *(unsigned*)(Wt + (size_t)(n0 + r) * 1024 + k0 + cp) = lo | (hi << 16);
    }
}

// ---------------------------------------------------------------------------
// K1: QKV GEMM (all bf16). C[8192,3072] = Xb @ Wt^T + b
// Q -> [B,H,S,64].  K,V -> FRAGMENT-PACKED layouts so attn's bf16x8 loads
// are lane-contiguous (1 KB per wave load, perfectly coalesced):
//   Kf[bh][kt(8)][kk(2)][j(8)][lane(64)][t(8)]   (kt,j,lcol_k <- key pos;
//                                                 kk,quad_k,t <- feature)
//   Vf[bh][kt(8)][kk2(4)][jo(4)][lane(64)][t(8)] (kt,kk2,quad_v,t <- key pos;
//                                                 jo,lcol_v <- d_out)
// ---------------------------------------------------------------------------
__global__ __launch_bounds__(256) void qkv_gemm(
    const unsigned short* __restrict__ Xb,   // [8192][1024] bf16
    const unsigned short* __restrict__ Wt,   // [3072][1024] bf16 = W^T
    const float* __restrict__ bq,
    unsigned short* __restrict__ Qb,
    unsigned short* __restrict__ Kf,
    unsigned short* __restrict__ Vf)
{
    __shared__ __align__(16) short As[128 * 64];
    __shared__ __align__(16) short Bs[128 * 64];

    const int m0 = blockIdx.y * 128, n0 = blockIdx.x * 128;
    const int tid = threadIdx.x;
    const int wave = tid >> 6, lane = tid & 63;
    const int quad = lane >> 4, lcol = lane & 15;
    const int wrow = (wave >> 1) * 64, wcol = (wave & 1) * 64;

    f32x4 acc[4][4];
#pragma unroll
    for (int i = 0; i < 4; i++)
#pragma unroll
        for (int j = 0; j < 4; j++) acc[i][j] = (f32x4){0.f, 0.f, 0.f, 0.f};

    const int sr = tid >> 3;          // 0..31: row within 32-row pass
    const int sc8 = (tid & 7) * 8;    // col (shorts)

    for (int k0 = 0; k0 < 1024; k0 += 64) {
        __syncthreads();
#pragma unroll
        for (int p = 0; p < 4; p++) {
            glds16(Xb + (size_t)(m0 + p * 32 + sr) * 1024 + k0 + sc8,
                   &As[(p * 32 + sr) * 64 + sc8]);
            glds16(Wt + (size_t)(n0 + p * 32 + sr) * 1024 + k0 + sc8,
                   &Bs[(p * 32 + sr) * 64 + sc8]);
        }
        __syncthreads();
#pragma unroll
        for (int kk = 0; kk < 2; kk++) {
            int ko = kk * 32 + quad * 8;
            bf16x8 a[4], b[4];
#pragma unroll
            for (int i = 0; i < 4; i++)
                a[i] = *(const bf16x8*)(&As[(wrow + 16 * i + lcol) * 64 + ko]);
#pragma unroll
            for (int j = 0; j < 4; j++)
                b[j] = *(const bf16x8*)(&Bs[(wcol + 16 * j + lcol) * 64 + ko]);
#pragma unroll
            for (int i = 0; i < 4; i++)
#pragma unroll
                for (int j = 0; j < 4; j++)
                    acc[i][j] = __builtin_amdgcn_mfma_f32_16x16x32_bf16(
                        a[i], b[j], acc[i][j], 0, 0, 0);
        }
    }

    // epilogue: +bias (fp32); scatter to Q / Kf / Vf
#pragma unroll
    for (int j = 0; j < 4; j++) {
        int cc = n0 + wcol + 16 * j + lcol;     // [0,3072)
        float bias = bq[cc];
        int which = cc >> 10, d = cc & 1023;
        int h = d >> 6, e = d & 63;
        if (which == 0) {
            // Q -> [B,H,S,64]
#pragma unroll
            for (int i = 0; i < 4; i++) {
#pragma unroll
                for (int reg = 0; reg < 4; reg++) {
                    int r = m0 + wrow + 16 * i + quad * 4 + reg;   // [0,8192)
                    int bb = r >> 10, s = r & 1023;
                    Qb[(size_t)((bb * 16 + h) * 1024 + s) * 64 + e] =
                        f2b(acc[i][j][reg] + bias);
                }
            }
        } else if (which == 1) {
            // K -> fragment-packed Kf
            int kk_k = e >> 5, quad_k = (e >> 3) & 3, t_k = e & 7;
#pragma unroll
            for (int i = 0; i < 4; i++) {
#pragma unroll
                for (int reg = 0; reg < 4; reg++) {
                    int r = m0 + wrow + 16 * i + quad * 4 + reg;
                    int bb = r >> 10, s = r & 1023;
                    int kt_k = s >> 7, j_k = (s >> 4) & 7, lcol_k = s & 15;
                    size_t idx =
                        ((((size_t)(bb * 16 + h) * 8 + kt_k) * 2 + kk_k) * 8 + j_k) * 512
                        + (quad_k * 16 + lcol_k) * 8 + t_k;
                    Kf[idx] = f2b(acc[i][j][reg] + bias);
                }
            }
        } else {
            // V -> fragment-packed Vf (4 consecutive s pack into ushort4)
            int jo_v = e >> 4, lcol_v = e & 15;
#pragma unroll
            for (int i = 0; i < 4; i++) {
                int r0 = m0 + wrow + 16 * i + quad * 4;
                int bb = r0 >> 10, s0 = r0 & 1023;
                int kt_v = s0 >> 7, kk2_v = (s0 >> 5) & 3;
                int quad_v = (s0 >> 3) & 3, t0 = s0 & 7;       // t0 in {0,4}
                ushort4 pk;
                pk.x = f2b(acc[i][j][0] + bias);
                pk.y = f2b(acc[i][j][1] + bias);
                pk.z = f2b(acc[i][j][2] + bias);
                pk.w = f2b(acc[i][j][3] + bias);
                size_t base =
                    ((((size_t)(bb * 16 + h) * 8 + kt_v) * 4 + kk2_v) * 4 + jo_v) * 512
                    + (quad_v * 16 + lcol_v) * 8 + t0;
                *(ushort4*)(Vf + base) = pk;
            }
        }
    }
}

// ---------------------------------------------------------------------------
// K2: causal flash attention — barrier-free, XCD-balanced, coalesced frags.
// Grid (8, 128); flat block id = x + 8y round-robins XCD = x, so qt must be
// a per-y-chunk permutation of x or XCD0 gets all the heavy diagonals:
//   c=(bh>>5)&3:  qt = x, 7-x, x^4, 7-(x^4)  -> every XCD gets 576 tiles,
//   every CU's 4 co-resident blocks (LDS 34.8 KB -> 4 blocks/CU) sum to 18.
// K/V read directly from fragment-packed global (1 KB contiguous per load,
// L2-resident 256 KB/head). Ps is wave-private -> zero __syncthreads.
// ---------------------------------------------------------------------------
__global__ __launch_bounds__(256) void attn_kern(
    const unsigned short* __restrict__ Qb,
    const unsigned short* __restrict__ Kf,
    const unsigned short* __restrict__ Vf,
    unsigned short* __restrict__ Ob)
{
    __shared__ __align__(16) short Ps[128 * 136];   // P: [q][key], 34.8 KB

    const int xb = blockIdx.x;                      // 0..7
    const int bh = blockIdx.y;                      // 0..127
    const int c4 = (bh >> 5) & 3;
    const int xv = (c4 & 2) ? (xb ^ 4) : xb;
    const int qt = (c4 & 1) ? (7 - xv) : xv;
    const int q0 = qt * 128;
    const unsigned short* Qp = Qb + (size_t)bh * 65536;
    const unsigned short* Kp = Kf + (size_t)bh * 65536;
    const unsigned short* Vp = Vf + (size_t)bh * 65536;

    const int tid = threadIdx.x;
    const int wave = tid >> 6, lane = tid & 63;
    const int quad = lane >> 4, lcol = lane & 15;

    // Q fragments (A-layout: m=lane&15, k=quad*8+j); wave owns 32 q-rows
    bf16x8 qa[2][2];
#pragma unroll
    for (int i = 0; i < 2; i++)
#pragma unroll
        for (int kk = 0; kk < 2; kk++)
            qa[i][kk] = *(const bf16x8*)(Qp + (size_t)(q0 + wave * 32 + 16 * i + lcol) * 64
                                         + kk * 32 + quad * 8);

    f32x4 o_acc[2][4];
#pragma unroll
    for (int i = 0; i < 2; i++)
#pragma unroll
        for (int jo = 0; jo < 4; jo++) o_acc[i][jo] = (f32x4){0.f, 0.f, 0.f, 0.f};
    float l_loc[2][4];
#pragma unroll
    for (int i = 0; i < 2; i++)
#pragma unroll
        for (int r = 0; r < 4; r++) l_loc[i][r] = 0.f;

    const float sc2 = 0.0450711882f;  // log2(e)/32  (scale folded into exp2)

    for (int kt = 0; kt <= qt; kt++) {
        const bool diag = (kt == qt);
        const int jstore = diag ? (2 * wave + 1) : 7;   // max live j-tile

        // S = Q K^T   (Kf: 1 KB contiguous per (kt,kk,j) load)
        f32x4 sc[2][8];
#pragma unroll
        for (int i = 0; i < 2; i++)
#pragma unroll
            for (int j = 0; j < 8; j++) sc[i][j] = (f32x4){0.f, 0.f, 0.f, 0.f};
#pragma unroll
        for (int kk = 0; kk < 2; kk++) {
            bf16x8 kb[8];
#pragma unroll
            for (int j = 0; j < 8; j++)
                if (j <= jstore)
                    kb[j] = *(const bf16x8*)(Kp
                        + ((size_t)((kt * 2 + kk) * 8 + j) << 9) + lane * 8);
#pragma unroll
            for (int i = 0; i < 2; i++)
#pragma unroll
                for (int j = 0; j < 8; j++)
                    if (j <= (diag ? (2 * wave + i) : 7))
                        sc[i][j] = __builtin_amdgcn_mfma_f32_16x16x32_bf16(
                            qa[i][kk], kb[j], sc[i][j], 0, 0, 0);
        }

        // max-free softmax: p = exp2(s*log2e/32), l accumulates lane-locally.
        // Ps rows written here belong to THIS wave only (rows [32w,32w+32)).
#pragma unroll
        for (int i = 0; i < 2; i++) {
#pragma unroll
            for (int reg = 0; reg < 4; reg++) {
                int prow = wave * 32 + 16 * i + quad * 4 + reg;  // local q row
                float rsum = 0.f;
#pragma unroll
                for (int j = 0; j < 8; j++) {
                    if (j <= jstore) {
                        float p = exp2f(sc[i][j][reg] * sc2);
                        if (diag && (16 * j + lcol) > prow) p = 0.f;
                        rsum += p;
                        Ps[prow * 136 + 16 * j + lcol] = (short)f2b(p);
                    }
                }
                l_loc[i][reg] += rsum;
            }
        }

        // O += P @ V   (P A-layout from wave-private Ps rows; Vf 1 KB loads)
#pragma unroll
        for (int kk2 = 0; kk2 < 4; kk2++) {
            if (!diag || kk2 <= wave) {
                bf16x8 pa[2], vb[4];
#pragma unroll
                for (int i = 0; i < 2; i++)
                    pa[i] = *(const bf16x8*)(&Ps[(wave * 32 + 16 * i + lcol) * 136
                                                 + kk2 * 32 + quad * 8]);
#pragma unroll
                for (int jo = 0; jo < 4; jo++)
                    vb[jo] = *(const bf16x8*)(Vp
                        + ((size_t)((kt * 4 + kk2) * 4 + jo) << 9) + lane * 8);
#pragma unroll
                for (int i = 0; i < 2; i++)
#pragma unroll
                    for (int jo = 0; jo < 4; jo++)
                        o_acc[i][jo] = __builtin_amdgcn_mfma_f32_16x16x32_bf16(
                            pa[i], vb[jo], o_acc[i][jo], 0, 0, 0);
            }
        }
    }

    // single final l reduction (16 lanes of a quad share a row)
#pragma unroll
    for (int i = 0; i < 2; i++)
#pragma unroll
        for (int reg = 0; reg < 4; reg++) {
            float l = l_loc[i][reg];
            l += __shfl_xor(l, 1);
            l += __shfl_xor(l, 2);
            l += __shfl_xor(l, 4);
            l += __shfl_xor(l, 8);
            l_loc[i][reg] = l;
        }

    // write O -> [B, S, H*hd] bf16
    const int b = bh >> 4, h = bh & 15;
#pragma unroll
    for (int i = 0; i < 2; i++) {
#pragma unroll
        for (int reg = 0; reg < 4; reg++) {
            int q = q0 + wave * 32 + 16 * i + quad * 4 + reg;
            float inv = 1.0f / l_loc[i][reg];
#pragma unroll
            for (int jo = 0; jo < 4; jo++) {
                int e = 16 * jo + lcol;
                Ob[(size_t)(b * 1024 + q) * 1024 + h * 64 + e] =
                    f2b(o_acc[i][jo][reg] * inv);
            }
        }
    }
}

// ---------------------------------------------------------------------------
// K3: out proj. P2[8192,1024](bf16) = O @ Wout + bout + X(fp32 residual)
// ---------------------------------------------------------------------------
__global__ __launch_bounds__(256) void out_gemm(
    const unsigned short* __restrict__ O,
    const unsigned short* __restrict__ Wt2,  // [1024][1024] bf16 = Wout^T
    const float* __restrict__ bo,
    const float* __restrict__ X,
    unsigned short* __restrict__ P2)
{
    __shared__ __align__(16) short As[128 * 64];
    __shared__ __align__(16) short Bs[128 * 64];

    const int m0 = blockIdx.y * 128, n0 = blockIdx.x * 128;
    const int tid = threadIdx.x;
    const int wave = tid >> 6, lane = tid & 63;
    const int quad = lane >> 4, lcol = lane & 15;
    const int wrow = (wave >> 1) * 64, wcol = (wave & 1) * 64;

    f32x4 acc[4][4];
#pragma unroll
    for (int i = 0; i < 4; i++)
#pragma unroll
        for (int j = 0; j < 4; j++) acc[i][j] = (f32x4){0.f, 0.f, 0.f, 0.f};

    const int sr = tid >> 3;
    const int sc8 = (tid & 7) * 8;

    for (int k0 = 0; k0 < 1024; k0 += 64) {
        __syncthreads();
#pragma unroll
        for (int p = 0; p < 4; p++) {
            glds16(O + (size_t)(m0 + p * 32 + sr) * 1024 + k0 + sc8,
                   &As[(p * 32 + sr) * 64 + sc8]);
            glds16(Wt2 + (size_t)(n0 + p * 32 + sr) * 1024 + k0 + sc8,
                   &Bs[(p * 32 + sr) * 64 + sc8]);
        }
        __syncthreads();
#pragma unroll
        for (int kk = 0; kk < 2; kk++) {
            int ko = kk * 32 + quad * 8;
            bf16x8 a[4], b[4];
#pragma unroll
            for (int i = 0; i < 4; i++)
                a[i] = *(const bf16x8*)(&As[(wrow + 16 * i + lcol) * 64 + ko]);
#pragma unroll
            for (int j = 0; j < 4; j++)
                b[j] = *(const bf16x8*)(&Bs[(wcol + 16 * j + lcol) * 64 + ko]);
#pragma unroll
            for (int i = 0; i < 4; i++)
#pragma unroll
                for (int j = 0; j < 4; j++)
                    acc[i][j] = __builtin_amdgcn_mfma_f32_16x16x32_bf16(
                        a[i], b[j], acc[i][j], 0, 0, 0);
        }
    }

#pragma unroll
    for (int j = 0; j < 4; j++) {
        int c = n0 + wcol + 16 * j + lcol;
        float bias = bo[c];
#pragma unroll
        for (int i = 0; i < 4; i++) {
#pragma unroll
            for (int reg = 0; reg < 4; reg++) {
                int r = m0 + wrow + 16 * i + quad * 4 + reg;
                float v = acc[i][j][reg] + bias + X[(size_t)r * 1024 + c];
                P2[(size_t)r * 1024 + c] = f2b(v);
            }
        }
    }
}

// ---------------------------------------------------------------------------
// K4: LayerNorm over last dim (1024), bf16 in / fp32 out, one block per row
// ---------------------------------------------------------------------------
__global__ __launch_bounds__(256) void ln_kern(
    const unsigned short* __restrict__ P2,
    const float* __restrict__ G,
    const float* __restrict__ Bt,
    float* __restrict__ out)
{
    const int row = blockIdx.x, tid = threadIdx.x;
    const size_t base = (size_t)row * 1024 + tid * 4;

    int2 raw = *(const int2*)(P2 + base);
    float v[4];
    v[0] = b2f((unsigned short)(raw.x & 0xffff));
    v[1] = b2f((unsigned short)((unsigned)raw.x >> 16));
    v[2] = b2f((unsigned short)(raw.y & 0xffff));
    v[3] = b2f((unsigned short)((unsigned)raw.y >> 16));

    float sum = v[0] + v[1] + v[2] + v[3];
    float sq = v[0] * v[0] + v[1] * v[1] + v[2] * v[2] + v[3] * v[3];
#pragma unroll
    for (int m = 1; m < 64; m <<= 1) {
        sum += __shfl_xor(sum, m);
        sq += __shfl_xor(sq, m);
    }
    __shared__ float rs[4], rq[4];
    const int wave = tid >> 6, lane = tid & 63;
    if (lane == 0) { rs[wave] = sum; rq[wave] = sq; }
    __syncthreads();
    sum = rs[0] + rs[1] + rs[2] + rs[3];
    sq = rq[0] + rq[1] + rq[2] + rq[3];

    float mean = sum * (1.0f / 1024.0f);
    float var = fmaxf(sq * (1.0f / 1024.0f) - mean * mean, 0.0f);
    float rstd = rsqrtf(var + 1e-5f);

    float4 g = *(const float4*)(G + tid * 4);
    float4 be = *(const float4*)(Bt + tid * 4);

    float4 o;
    o.x = (v[0] - mean) * rstd * g.x + be.x;
    o.y = (v[1] - mean) * rstd * g.y + be.y;
    o.z = (v[2] - mean) * rstd * g.z + be.z;
    o.w = (v[3] - mean) * rstd * g.w + be.w;
    *(float4*)(out + base) = o;
}

// ---------------------------------------------------------------------------
// Buffer plan:
//   d_out (32 MB): Qb bf16 @0, Ob bf16 @16M; final fp32 result overwrites.
//   d_ws  (56 MB): Kf @0, Vf @16M, Wt2 @32M (2M), Xb @34M (16M), Wt @50M (6M)
//   P2 bf16 @34M aliases Xb (dead after qkv_gemm).
// ---------------------------------------------------------------------------
extern "C" void kernel_launch(void* const* d_in, const int* in_sizes, int n_in,
                              void* d_out, int out_size, void* d_ws, size_t ws_size,
                              hipStream_t stream) {
    const float* x    = (const float*)d_in[0];
    const float* Wqkv = (const float*)d_in[1];
    const float* bqkv = (const float*)d_in[2];
    const float* Wout = (const float*)d_in[3];
    const float* bout = (const float*)d_in[4];
    const float* gam  = (const float*)d_in[5];
    const float* bet  = (const float*)d_in[6];
    float* out = (float*)d_out;

    char* ws = (char*)d_ws;
    const size_t MB = (size_t)1024 * 1024;

    unsigned short* Qb  = (unsigned short*)d_out;
    unsigned short* Ob  = (unsigned short*)d_out + 8388608;
    unsigned short* Kf  = (unsigned short*)(ws);
    unsigned short* Vf  = (unsigned short*)(ws + 16 * MB);
    unsigned short* Wt2 = (unsigned short*)(ws + 32 * MB);
    unsigned short* Xb  = (unsigned short*)(ws + 34 * MB);
    unsigned short* Wt  = (unsigned short*)(ws + 50 * MB);
    unsigned short* P2  = (unsigned short*)(ws + 34 * MB);   // alias Xb

    cvt_bf16<<<4096, 256, 0, stream>>>(x, Xb);
    transpose_cvt<<<dim3(48, 16), 256, 0, stream>>>(Wqkv, Wt, 3072);
    transpose_cvt<<<dim3(16, 16), 256, 0, stream>>>(Wout, Wt2, 1024);
    qkv_gemm<<<dim3(24, 64), 256, 0, stream>>>(Xb, Wt, bqkv, Qb, Kf, Vf);
    attn_kern<<<dim3(8, 128), 256, 0, stream>>>(Qb, Kf, Vf, Ob);
    out_gemm<<<dim3(8, 64), 256, 0, stream>>>(Ob, Wt2, bout, x, P2);
    ln_kern<<<8192, 256, 0, stream>>>(P2, gam, bet, out);
}

// Round 3
// 279.402 us; speedup vs baseline: 1.3979x; 1.1533x over previous
//
#include <hip/hip_runtime.h>
#include <math.h>

typedef __attribute__((ext_vector_type(8))) short bf16x8;
typedef __attribute__((ext_vector_type(4))) float f32x4;

#define DEV __device__ __forceinline__

DEV unsigned short f2b(float f) {
    union { float f; unsigned u; } x;
    x.f = f;
    unsigned r = x.u + 0x7fff + ((x.u >> 16) & 1);  // RNE
    return (unsigned short)(r >> 16);
}
DEV float b2f(unsigned short u) {
    union { unsigned u; float f; } x;
    x.u = ((unsigned)u) << 16;
    return x.f;
}

// async global->LDS, 16B per lane; LDS dest must be wave-uniform base + lane*16
DEV void glds16(const void* g, void* l) {
    __builtin_amdgcn_global_load_lds(
        (const __attribute__((address_space(1))) void*)g,
        (__attribute__((address_space(3))) void*)l, 16, 0, 0);
}

// ---------------------------------------------------------------------------
// P0a: fp32 -> bf16 elementwise (X pre-convert)
// ---------------------------------------------------------------------------
__global__ __launch_bounds__(256) void cvt_bf16(
    const float* __restrict__ in, unsigned short* __restrict__ out)
{
    int i = (blockIdx.x * 256 + threadIdx.x) * 8;
    float4 a = *(const float4*)(in + i);
    float4 b = *(const float4*)(in + i + 4);
    int4 tv;
    short* tp = reinterpret_cast<short*>(&tv);
    tp[0] = (short)f2b(a.x); tp[1] = (short)f2b(a.y);
    tp[2] = (short)f2b(a.z); tp[3] = (short)f2b(a.w);
    tp[4] = (short)f2b(b.x); tp[5] = (short)f2b(b.y);
    tp[6] = (short)f2b(b.z); tp[7] = (short)f2b(b.w);
    *(int4*)(out + i) = tv;
}

// ---------------------------------------------------------------------------
// P0b: W fp32 [1024][N] -> W^T bf16 [N][1024]   (64x64 LDS tiles)
// ---------------------------------------------------------------------------
__global__ __launch_bounds__(256) void transpose_cvt(
    const float* __restrict__ W, unsigned short* __restrict__ Wt, int N)
{
    __shared__ short S[64 * 65];
    const int n0 = blockIdx.x * 64, k0 = blockIdx.y * 64;
    const int tid = threadIdx.x;
#pragma unroll
    for (int p = 0; p < 16; p++) {
        int idx = p * 256 + tid;
        int r = idx >> 6, c = idx & 63;          // r = k, c = n (coalesced read)
        S[c * 65 + r] = (short)f2b(W[(size_t)(k0 + r) * N + n0 + c]);
    }
    __syncthreads();
#pragma unroll
    for (int p = 0; p < 8; p++) {
        int idx = p * 256 + tid;
        int r = idx >> 5, cp = (idx & 31) * 2;   // r = n, cp = k pair
        unsigned lo = (unsigned short)S[r * 65 + cp];
        unsigned hi = (unsigned short)S[r * 65 + cp + 1];
        *(unsigned*)(Wt + (size_t)(n0 + r) * 1024 + k0 + cp) = lo | (hi << 16);
    }
}

// ---------------------------------------------------------------------------
// K1: QKV GEMM (all bf16). C[8192,3072] = Xb @ Wt^T + b
// Q -> [B,H,S,64].  K,V -> FRAGMENT-PACKED layouts so attn's bf16x8 loads
// are lane-contiguous (1 KB per wave load, perfectly coalesced):
//   Kf[bh][kt(8)][kk(2)][j(8)][lane(64)][t(8)]   (kt,j,lcol_k <- key pos;
//                                                 kk,quad_k,t <- feature)
//   Vf[bh][kt(8)][kk2(4)][jo(4)][lane(64)][t(8)] (kt,kk2,quad_v,t <- key pos;
//                                                 jo,lcol_v <- d_out)
// ---------------------------------------------------------------------------
__global__ __launch_bounds__(256) void qkv_gemm(
    const unsigned short* __restrict__ Xb,   // [8192][1024] bf16
    const unsigned short* __restrict__ Wt,   // [3072][1024] bf16 = W^T
    const float* __restrict__ bq,
    unsigned short* __restrict__ Qb,
    unsigned short* __restrict__ Kf,
    unsigned short* __restrict__ Vf)
{
    __shared__ __align__(16) short As[128 * 64];
    __shared__ __align__(16) short Bs[128 * 64];

    const int m0 = blockIdx.y * 128, n0 = blockIdx.x * 128;
    const int tid = threadIdx.x;
    const int wave = tid >> 6, lane = tid & 63;
    const int quad = lane >> 4, lcol = lane & 15;
    const int wrow = (wave >> 1) * 64, wcol = (wave & 1) * 64;

    f32x4 acc[4][4];
#pragma unroll
    for (int i = 0; i < 4; i++)
#pragma unroll
        for (int j = 0; j < 4; j++) acc[i][j] = (f32x4){0.f, 0.f, 0.f, 0.f};

    const int sr = tid >> 3;          // 0..31: row within 32-row pass
    const int sc8 = (tid & 7) * 8;    // col (shorts)

    for (int k0 = 0; k0 < 1024; k0 += 64) {
        __syncthreads();
#pragma unroll
        for (int p = 0; p < 4; p++) {
            glds16(Xb + (size_t)(m0 + p * 32 + sr) * 1024 + k0 + sc8,
                   &As[(p * 32 + sr) * 64 + sc8]);
            glds16(Wt + (size_t)(n0 + p * 32 + sr) * 1024 + k0 + sc8,
                   &Bs[(p * 32 + sr) * 64 + sc8]);
        }
        __syncthreads();
#pragma unroll
        for (int kk = 0; kk < 2; kk++) {
            int ko = kk * 32 + quad * 8;
            bf16x8 a[4], b[4];
#pragma unroll
            for (int i = 0; i < 4; i++)
                a[i] = *(const bf16x8*)(&As[(wrow + 16 * i + lcol) * 64 + ko]);
#pragma unroll
            for (int j = 0; j < 4; j++)
                b[j] = *(const bf16x8*)(&Bs[(wcol + 16 * j + lcol) * 64 + ko]);
#pragma unroll
            for (int i = 0; i < 4; i++)
#pragma unroll
                for (int j = 0; j < 4; j++)
                    acc[i][j] = __builtin_amdgcn_mfma_f32_16x16x32_bf16(
                        a[i], b[j], acc[i][j], 0, 0, 0);
        }
    }

    // epilogue: +bias (fp32); scatter to Q / Kf / Vf
#pragma unroll
    for (int j = 0; j < 4; j++) {
        int cc = n0 + wcol + 16 * j + lcol;     // [0,3072)
        float bias = bq[cc];
        int which = cc >> 10, d = cc & 1023;
        int h = d >> 6, e = d & 63;
        if (which == 0) {
            // Q -> [B,H,S,64]
#pragma unroll
            for (int i = 0; i < 4; i++) {
#pragma unroll
                for (int reg = 0; reg < 4; reg++) {
                    int r = m0 + wrow + 16 * i + quad * 4 + reg;   // [0,8192)
                    int bb = r >> 10, s = r & 1023;
                    Qb[(size_t)((bb * 16 + h) * 1024 + s) * 64 + e] =
                        f2b(acc[i][j][reg] + bias);
                }
            }
        } else if (which == 1) {
            // K -> fragment-packed Kf
            int kk_k = e >> 5, quad_k = (e >> 3) & 3, t_k = e & 7;
#pragma unroll
            for (int i = 0; i < 4; i++) {
#pragma unroll
                for (int reg = 0; reg < 4; reg++) {
                    int r = m0 + wrow + 16 * i + quad * 4 + reg;
                    int bb = r >> 10, s = r & 1023;
                    int kt_k = s >> 7, j_k = (s >> 4) & 7, lcol_k = s & 15;
                    size_t idx =
                        ((((size_t)(bb * 16 + h) * 8 + kt_k) * 2 + kk_k) * 8 + j_k) * 512
                        + (quad_k * 16 + lcol_k) * 8 + t_k;
                    Kf[idx] = f2b(acc[i][j][reg] + bias);
                }
            }
        } else {
            // V -> fragment-packed Vf (4 consecutive s pack into ushort4)
            int jo_v = e >> 4, lcol_v = e & 15;
#pragma unroll
            for (int i = 0; i < 4; i++) {
                int r0 = m0 + wrow + 16 * i + quad * 4;
                int bb = r0 >> 10, s0 = r0 & 1023;
                int kt_v = s0 >> 7, kk2_v = (s0 >> 5) & 3;
                int quad_v = (s0 >> 3) & 3, t0 = s0 & 7;       // t0 in {0,4}
                ushort4 pk;
                pk.x = f2b(acc[i][j][0] + bias);
                pk.y = f2b(acc[i][j][1] + bias);
                pk.z = f2b(acc[i][j][2] + bias);
                pk.w = f2b(acc[i][j][3] + bias);
                size_t base =
                    ((((size_t)(bb * 16 + h) * 8 + kt_v) * 4 + kk2_v) * 4 + jo_v) * 512
                    + (quad_v * 16 + lcol_v) * 8 + t0;
                *(ushort4*)(Vf + base) = pk;
            }
        }
    }
}

// ---------------------------------------------------------------------------
// K2: causal flash attention — EQUAL-WORK blocks + SWAPPED-OPERAND QK^T.
//
// Work balance: block x in [0,8) handles pair p=x>>1 -> q-tiles (p, 7-p),
// half h=x&1 -> 64-row strip of each. Every block = exactly 9 tile-strips,
// so all 1024 blocks are resident AND finish together (flat 16 waves/CU).
// Each wave owns 16 q-rows; Ps slice is wave-private -> zero __syncthreads.
//
// Swapped QK: S^T = mfma(K_frag, Q_frag) puts q on lane&15 and 4 CONSECUTIVE
// keys in the 4 C-regs -> Ps store is one ushort4 per 16-key tile (b64 at
// the bank floor, vs 64 scalar b16 before), and l is a pure per-lane
// accumulator (2 shfl_xor per pass total). PV path and Kf/Vf/Qb layouts
// are unchanged.
// ---------------------------------------------------------------------------
__global__ __launch_bounds__(256, 4) void attn_kern(
    const unsigned short* __restrict__ Qb,
    const unsigned short* __restrict__ Kf,
    const unsigned short* __restrict__ Vf,
    unsigned short* __restrict__ Ob)
{
    __shared__ __align__(16) short Ps[64 * 136];    // 17.4 KB, wave-private slices

    const int xb = blockIdx.x;                      // 0..7
    const int bh = blockIdx.y;                      // 0..127
    const int pr = xb >> 1;                         // pair 0..3
    const int hf = xb & 1;                          // half-strip 0..1
    const unsigned short* Qp = Qb + (size_t)bh * 65536;
    const unsigned short* Kp = Kf + (size_t)bh * 65536;
    const unsigned short* Vp = Vf + (size_t)bh * 65536;

    const int tid = threadIdx.x;
    const int wave = tid >> 6, lane = tid & 63;
    const int quad = lane >> 4, lcol = lane & 15;
    const int hw4 = hf * 4 + wave;                  // 0..7: 16-row strip in tile
    const int qloc = hw4 * 16 + lcol;               // lane's q within its tile

    const float sc2 = 0.0450711882f;  // log2(e)/32  (scale folded into exp2)
    const int b = bh >> 4, h = bh & 15;

    for (int pass = 0; pass < 2; pass++) {
        const int qt = pass ? (7 - pr) : pr;        // q-tile index 0..7
        const int q0 = qt * 128 + hf * 64 + wave * 16;  // wave's first q row

        // Q fragments (B-operand: q=lane&15, k=quad*8+t)
        bf16x8 qa[2];
#pragma unroll
        for (int kk = 0; kk < 2; kk++)
            qa[kk] = *(const bf16x8*)(Qp + (size_t)(q0 + lcol) * 64
                                      + kk * 32 + quad * 8);

        f32x4 o_acc[4];
#pragma unroll
        for (int jo = 0; jo < 4; jo++) o_acc[jo] = (f32x4){0.f, 0.f, 0.f, 0.f};
        float l_loc = 0.f;

        for (int kt = 0; kt <= qt; kt++) {
            const bool diag = (kt == qt);
            const int jmax = diag ? hw4 : 7;        // max live 16-key tile
            const int kk2max = diag ? (hw4 >> 1) : 3;

            // S^T = K Q^T : lane holds S^T[key=16j+quad*4+reg][q=lcol]
            f32x4 scT[8];
#pragma unroll
            for (int j = 0; j < 8; j++) scT[j] = (f32x4){0.f, 0.f, 0.f, 0.f};
#pragma unroll
            for (int kk = 0; kk < 2; kk++) {
                bf16x8 kb[8];
#pragma unroll
                for (int j = 0; j < 8; j++)
                    if (j <= jmax)
                        kb[j] = *(const bf16x8*)(Kp
                            + ((size_t)((kt * 2 + kk) * 8 + j) << 9) + lane * 8);
#pragma unroll
                for (int j = 0; j < 8; j++)
                    if (j <= jmax)
                        scT[j] = __builtin_amdgcn_mfma_f32_16x16x32_bf16(
                            kb[j], qa[kk], scT[j], 0, 0, 0);
            }

            // max-free softmax; packed b64 store to Ps[q][key] (4 consecutive
            // keys per reg-quad). l accumulates per-lane (q = lcol fixed).
#pragma unroll
            for (int j = 0; j < 8; j++) {
                if (j <= jmax) {
                    float pv[4];
#pragma unroll
                    for (int r = 0; r < 4; r++) {
                        float p = exp2f(scT[j][r] * sc2);
                        if (diag && (16 * j + quad * 4 + r) > qloc) p = 0.f;
                        l_loc += p;
                        pv[r] = p;
                    }
                    ushort4 pk;
                    pk.x = f2b(pv[0]); pk.y = f2b(pv[1]);
                    pk.z = f2b(pv[2]); pk.w = f2b(pv[3]);
                    *(ushort4*)(&Ps[(wave * 16 + lcol) * 136 + 16 * j + quad * 4]) = pk;
                }
            }
            // diag with even jmax: PV's kk2max chunk reads tile jmax+1 -> zero it
            if (diag && !(jmax & 1)) {
                *(ushort4*)(&Ps[(wave * 16 + lcol) * 136 + 16 * (jmax + 1) + quad * 4]) =
                    (ushort4){0, 0, 0, 0};
            }

            // O += P @ V  (pa: A-layout b128 read of own rows; vb: 1 KB loads)
#pragma unroll
            for (int kk2 = 0; kk2 < 4; kk2++) {
                if (kk2 <= kk2max) {
                    bf16x8 pa = *(const bf16x8*)(&Ps[(wave * 16 + lcol) * 136
                                                     + kk2 * 32 + quad * 8]);
                    bf16x8 vb[4];
#pragma unroll
                    for (int jo = 0; jo < 4; jo++)
                        vb[jo] = *(const bf16x8*)(Vp
                            + ((size_t)((kt * 4 + kk2) * 4 + jo) << 9) + lane * 8);
#pragma unroll
                    for (int jo = 0; jo < 4; jo++)
                        o_acc[jo] = __builtin_amdgcn_mfma_f32_16x16x32_bf16(
                            pa, vb[jo], o_acc[jo], 0, 0, 0);
                }
            }
        }

        // l: sum the 4 quads (lanes with equal lcol hold the same q)
        l_loc += __shfl_xor(l_loc, 16);
        l_loc += __shfl_xor(l_loc, 32);
        float inv = 1.0f / l_loc;                   // inv for q = q0 + lcol
        float invq[4];
#pragma unroll
        for (int r = 0; r < 4; r++) invq[r] = __shfl(inv, quad * 4 + r);

        // write O -> [B, S, H*hd] bf16  (C-layout: row=q=quad*4+reg, col=d=16jo+lcol)
#pragma unroll
        for (int jo = 0; jo < 4; jo++) {
#pragma unroll
            for (int r = 0; r < 4; r++) {
                int q = q0 + quad * 4 + r;
                Ob[(size_t)(b * 1024 + q) * 1024 + h * 64 + 16 * jo + lcol] =
                    f2b(o_acc[jo][r] * invq[r]);
            }
        }
        l_loc = 0.f;
    }
}

// ---------------------------------------------------------------------------
// K3: out proj. P2[8192,1024](bf16) = O @ Wout + bout + X(fp32 residual)
// ---------------------------------------------------------------------------
__global__ __launch_bounds__(256) void out_gemm(
    const unsigned short* __restrict__ O,
    const unsigned short* __restrict__ Wt2,  // [1024][1024] bf16 = Wout^T
    const float* __restrict__ bo,
    const float* __restrict__ X,
    unsigned short* __restrict__ P2)
{
    __shared__ __align__(16) short As[128 * 64];
    __shared__ __align__(16) short Bs[128 * 64];

    const int m0 = blockIdx.y * 128, n0 = blockIdx.x * 128;
    const int tid = threadIdx.x;
    const int wave = tid >> 6, lane = tid & 63;
    const int quad = lane >> 4, lcol = lane & 15;
    const int wrow = (wave >> 1) * 64, wcol = (wave & 1) * 64;

    f32x4 acc[4][4];
#pragma unroll
    for (int i = 0; i < 4; i++)
#pragma unroll
        for (int j = 0; j < 4; j++) acc[i][j] = (f32x4){0.f, 0.f, 0.f, 0.f};

    const int sr = tid >> 3;
    const int sc8 = (tid & 7) * 8;

    for (int k0 = 0; k0 < 1024; k0 += 64) {
        __syncthreads();
#pragma unroll
        for (int p = 0; p < 4; p++) {
            glds16(O + (size_t)(m0 + p * 32 + sr) * 1024 + k0 + sc8,
                   &As[(p * 32 + sr) * 64 + sc8]);
            glds16(Wt2 + (size_t)(n0 + p * 32 + sr) * 1024 + k0 + sc8,
                   &Bs[(p * 32 + sr) * 64 + sc8]);
        }
        __syncthreads();
#pragma unroll
        for (int kk = 0; kk < 2; kk++) {
            int ko = kk * 32 + quad * 8;
            bf16x8 a[4], b[4];
#pragma unroll
            for (int i = 0; i < 4; i++)
                a[i] = *(const bf16x8*)(&As[(wrow + 16 * i + lcol) * 64 + ko]);
#pragma unroll
            for (int j = 0; j < 4; j++)
                b[j] = *(const bf16x8*)(&Bs[(wcol + 16 * j + lcol) * 64 + ko]);
#pragma unroll
            for (int i = 0; i < 4; i++)
#pragma unroll
                for (int j = 0; j < 4; j++)
                    acc[i][j] = __builtin_amdgcn_mfma_f32_16x16x32_bf16(
                        a[i], b[j], acc[i][j], 0, 0, 0);
        }
    }

#pragma unroll
    for (int j = 0; j < 4; j++) {
        int c = n0 + wcol + 16 * j + lcol;
        float bias = bo[c];
#pragma unroll
        for (int i = 0; i < 4; i++) {
#pragma unroll
            for (int reg = 0; reg < 4; reg++) {
                int r = m0 + wrow + 16 * i + quad * 4 + reg;
                float v = acc[i][j][reg] + bias + X[(size_t)r * 1024 + c];
                P2[(size_t)r * 1024 + c] = f2b(v);
            }
        }
    }
}

// ---------------------------------------------------------------------------
// K4: LayerNorm over last dim (1024), bf16 in / fp32 out, one block per row
// ---------------------------------------------------------------------------
__global__ __launch_bounds__(256) void ln_kern(
    const unsigned short* __restrict__ P2,
    const float* __restrict__ G,
    const float* __restrict__ Bt,
    float* __restrict__ out)
{
    const int row = blockIdx.x, tid = threadIdx.x;
    const size_t base = (size_t)row * 1024 + tid * 4;

    int2 raw = *(const int2*)(P2 + base);
    float v[4];
    v[0] = b2f((unsigned short)(raw.x & 0xffff));
    v[1] = b2f((unsigned short)((unsigned)raw.x >> 16));
    v[2] = b2f((unsigned short)(raw.y & 0xffff));
    v[3] = b2f((unsigned short)((unsigned)raw.y >> 16));

    float sum = v[0] + v[1] + v[2] + v[3];
    float sq = v[0] * v[0] + v[1] * v[1] + v[2] * v[2] + v[3] * v[3];
#pragma unroll
    for (int m = 1; m < 64; m <<= 1) {
        sum += __shfl_xor(sum, m);
        sq += __shfl_xor(sq, m);
    }
    __shared__ float rs[4], rq[4];
    const int wave = tid >> 6, lane = tid & 63;
    if (lane == 0) { rs[wave] = sum; rq[wave] = sq; }
    __syncthreads();
    sum = rs[0] + rs[1] + rs[2] + rs[3];
    sq = rq[0] + rq[1] + rq[2] + rq[3];

    float mean = sum * (1.0f / 1024.0f);
    float var = fmaxf(sq * (1.0f / 1024.0f) - mean * mean, 0.0f);
    float rstd = rsqrtf(var + 1e-5f);

    float4 g = *(const float4*)(G + tid * 4);
    float4 be = *(const float4*)(Bt + tid * 4);

    float4 o;
    o.x = (v[0] - mean) * rstd * g.x + be.x;
    o.y = (v[1] - mean) * rstd * g.y + be.y;
    o.z = (v[2] - mean) * rstd * g.z + be.z;
    o.w = (v[3] - mean) * rstd * g.w + be.w;
    *(float4*)(out + base) = o;
}

// ---------------------------------------------------------------------------
// Buffer plan:
//   d_out (32 MB): Qb bf16 @0, Ob bf16 @16M; final fp32 result overwrites.
//   d_ws  (56 MB): Kf @0, Vf @16M, Wt2 @32M (2M), Xb @34M (16M), Wt @50M (6M)
//   P2 bf16 @34M aliases Xb (dead after qkv_gemm).
// ---------------------------------------------------------------------------
extern "C" void kernel_launch(void* const* d_in, const int* in_sizes, int n_in,
                              void* d_out, int out_size, void* d_ws, size_t ws_size,
                              hipStream_t stream) {
    const float* x    = (const float*)d_in[0];
    const float* Wqkv = (const float*)d_in[1];
    const float* bqkv = (const float*)d_in[2];
    const float* Wout = (const float*)d_in[3];
    const float* bout = (const float*)d_in[4];
    const float* gam  = (const float*)d_in[5];
    const float* bet  = (const float*)d_in[6];
    float* out = (float*)d_out;

    char* ws = (char*)d_ws;
    const size_t MB = (size_t)1024 * 1024;

    unsigned short* Qb  = (unsigned short*)d_out;
    unsigned short* Ob  = (unsigned short*)d_out + 8388608;
    unsigned short* Kf  = (unsigned short*)(ws);
    unsigned short* Vf  = (unsigned short*)(ws + 16 * MB);
    unsigned short* Wt2 = (unsigned short*)(ws + 32 * MB);
    unsigned short* Xb  = (unsigned short*)(ws + 34 * MB);
    unsigned short* Wt  = (unsigned short*)(ws + 50 * MB);
    unsigned short* P2  = (unsigned short*)(ws + 34 * MB);   // alias Xb

    cvt_bf16<<<4096, 256, 0, stream>>>(x, Xb);
    transpose_cvt<<<dim3(48, 16), 256, 0, stream>>>(Wqkv, Wt, 3072);
    transpose_cvt<<<dim3(16, 16), 256, 0, stream>>>(Wout, Wt2, 1024);
    qkv_gemm<<<dim3(24, 64), 256, 0, stream>>>(Xb, Wt, bqkv, Qb, Kf, Vf);
    attn_kern<<<dim3(8, 128), 256, 0, stream>>>(Qb, Kf, Vf, Ob);
    out_gemm<<<dim3(8, 64), 256, 0, stream>>>(Ob, Wt2, bout, x, P2);
    ln_kern<<<8192, 256, 0, stream>>>(P2, gam, bet, out);
}